// Round 1
// baseline (651.935 us; speedup 1.0000x reference)
//
#include <hip/hip_runtime.h>
#include <math.h>

#define VOCAB 50000
#define DD 200
#define AA 32
#define RR 30000
#define LL 40
#define BB 10000

// ---------------------------------------------------------------------------
// Kernel 1: V = Y @ W_M   ([R,D] @ [D,D] -> [R,D])
// 32 rows per block; Y tile in LDS; thread t (<200) owns column d=t and keeps
// 32 row-accumulators in registers -> W_M element read exactly once per block.
// ---------------------------------------------------------------------------
__global__ __launch_bounds__(256) void v_gemm_kernel(
    const float* __restrict__ Y, const float* __restrict__ WM,
    float* __restrict__ V)
{
    __shared__ float yt[32 * DD];
    const int r0 = blockIdx.x * 32;
    const int tid = threadIdx.x;

    for (int i = tid; i < 32 * DD; i += 256) {
        int j = i / DD, e = i - j * DD;
        int r = r0 + j;
        yt[i] = (r < RR) ? Y[r * DD + e] : 0.f;
    }
    __syncthreads();

    if (tid < DD) {
        float acc[32];
        #pragma unroll
        for (int j = 0; j < 32; ++j) acc[j] = 0.f;
        for (int e = 0; e < DD; ++e) {
            float w = WM[e * DD + tid];           // coalesced across threads
            #pragma unroll
            for (int j = 0; j < 32; ++j) acc[j] += yt[j * DD + e] * w; // LDS broadcast
        }
        #pragma unroll
        for (int j = 0; j < 32; ++j) {
            int r = r0 + j;
            if (r < RR) V[r * DD + tid] = acc[j];
        }
    }
}

// ---------------------------------------------------------------------------
// Kernel 2: per-review attention -> p_t [R, A]
// One block (256 thr = 4 waves) per review r.
//   e_w[40][200] staged in LDS (32 KB), dx via wave-parallel dots,
//   softmax in wave 0, pooling column-parallel, A=32 proj via 8-lane groups.
// ---------------------------------------------------------------------------
__global__ __launch_bounds__(256) void attn_kernel(
    const int* __restrict__ hist, const float* __restrict__ emb,
    const float* __restrict__ V, const float* __restrict__ WW,
    const float* __restrict__ bW, float* __restrict__ PT)
{
    __shared__ float ew[LL * DD];   // 32000 B
    __shared__ float v[DD];
    __shared__ float zs[DD];
    __shared__ float dxs[LL];
    __shared__ float ax[LL];
    __shared__ int   widx[LL];

    const int r = blockIdx.x;
    const int tid = threadIdx.x;

    if (tid < LL) widx[tid] = hist[r * LL + tid];
    if (tid < DD) v[tid] = V[r * DD + tid];
    __syncthreads();

    // gather word embeddings (each 800B row coalesced; table is L3-resident)
    for (int i = tid; i < LL * DD; i += 256) {
        int l = i / DD, d = i - l * DD;
        ew[i] = emb[widx[l] * DD + d];
    }
    __syncthreads();

    const int wave = tid >> 6, lane = tid & 63;

    // dx[l] = e_w[l] . v   (each wave handles 10 of the 40 words)
    for (int l = wave; l < LL; l += 4) {
        float p = 0.f;
        for (int d = lane; d < DD; d += 64) p += ew[l * DD + d] * v[d];
        #pragma unroll
        for (int off = 32; off; off >>= 1) p += __shfl_xor(p, off);
        if (lane == 0) dxs[l] = p;
    }
    __syncthreads();

    // softmax over L=40 in wave 0
    if (wave == 0) {
        float x = (lane < LL) ? dxs[lane] : -INFINITY;
        float m = x;
        #pragma unroll
        for (int off = 32; off; off >>= 1) m = fmaxf(m, __shfl_xor(m, off));
        float e = (lane < LL) ? expf(x - m) : 0.f;
        float s = e;
        #pragma unroll
        for (int off = 32; off; off >>= 1) s += __shfl_xor(s, off);
        if (lane < LL) ax[lane] = e / s;
    }
    __syncthreads();

    // z_s[d] = sum_l ax[l] * e_w[l][d]
    if (tid < DD) {
        float acc = 0.f;
        for (int l = 0; l < LL; ++l) acc += ax[l] * ew[l * DD + tid];
        zs[tid] = acc;
    }
    __syncthreads();

    // p_t[r][a] = z_s . W_W[a] + b_W[a]   (8 threads per aspect)
    {
        int a = tid >> 3, j = tid & 7;
        float acc = 0.f;
        for (int d = j; d < DD; d += 8) acc += zs[d] * WW[a * DD + d];
        #pragma unroll
        for (int off = 4; off; off >>= 1) acc += __shfl_xor(acc, off);
        if (j == 0) PT[r * AA + a] = acc + bW[a];
    }
}

// ---------------------------------------------------------------------------
// Kernel 3: sparse [B,R] @ p_t [R,A] via gather + atomicAdd scatter.
// 32 lanes per nnz entry (one lane per aspect column).
// ---------------------------------------------------------------------------
__global__ __launch_bounds__(256) void spmm_kernel(
    const int* __restrict__ idx, const float* __restrict__ val,
    const float* __restrict__ PT, float* __restrict__ out, int nnz)
{
    int g = blockIdx.x * 256 + threadIdx.x;
    int n = g >> 5;
    if (n >= nnz) return;
    int a = g & 31;
    int row = idx[n];          // index[0][n]
    int col = idx[nnz + n];    // index[1][n]
    float w = val[n];
    atomicAdd(&out[row * AA + a], w * PT[col * AA + a]);
}

extern "C" void kernel_launch(void* const* d_in, const int* in_sizes, int n_in,
                              void* d_out, int out_size, void* d_ws, size_t ws_size,
                              hipStream_t stream) {
    const int*   hist = (const int*)d_in[0];
    const float* ypos = (const float*)d_in[1];
    const int*   uidx = (const int*)d_in[3];
    const float* uval = (const float*)d_in[4];
    const int*   iidx = (const int*)d_in[5];
    const float* ival = (const float*)d_in[6];
    const float* emb  = (const float*)d_in[8];
    const float* WM   = (const float*)d_in[9];
    const float* WW   = (const float*)d_in[10];
    const float* bW   = (const float*)d_in[11];

    float* V  = (float*)d_ws;            // [R, D]  24 MB
    float* PT = V + (size_t)RR * DD;     // [R, A]  3.84 MB
    float* out = (float*)d_out;          // [2, B, A]

    const int nnz = in_sizes[4];

    hipMemsetAsync(d_out, 0, (size_t)out_size * sizeof(float), stream);

    v_gemm_kernel<<<(RR + 31) / 32, 256, 0, stream>>>(ypos, WM, V);
    attn_kernel<<<RR, 256, 0, stream>>>(hist, emb, V, WW, bW, PT);

    const int spmm_blocks = (nnz * 32 + 255) / 256;
    spmm_kernel<<<spmm_blocks, 256, 0, stream>>>(uidx, uval, PT, out, nnz);
    spmm_kernel<<<spmm_blocks, 256, 0, stream>>>(iidx, ival, PT, out + BB * AA, nnz);
}

// Round 2
// 376.855 us; speedup vs baseline: 1.7299x; 1.7299x over previous
//
#include <hip/hip_runtime.h>
#include <math.h>

#define VOCAB 50000
#define DD 200
#define AA 32
#define RR 30000
#define LL 40
#define BB 10000

static __device__ __forceinline__ float bf2f(unsigned short u) {
    return __uint_as_float((unsigned int)u << 16);
}

// ---------------------------------------------------------------------------
// Kernel 0: convert emb table f32 -> bf16 (RNE). 10M elements, streaming.
// ---------------------------------------------------------------------------
__global__ __launch_bounds__(256) void cvt_bf16_kernel(
    const float* __restrict__ src, unsigned short* __restrict__ dst, int n4)
{
    int i = blockIdx.x * 256 + threadIdx.x;
    if (i >= n4) return;
    float4 f = ((const float4*)src)[i];
    ushort4 u;
    {
        unsigned int x;
        x = __float_as_uint(f.x); u.x = (unsigned short)((x + 0x7FFFu + ((x >> 16) & 1u)) >> 16);
        x = __float_as_uint(f.y); u.y = (unsigned short)((x + 0x7FFFu + ((x >> 16) & 1u)) >> 16);
        x = __float_as_uint(f.z); u.z = (unsigned short)((x + 0x7FFFu + ((x >> 16) & 1u)) >> 16);
        x = __float_as_uint(f.w); u.w = (unsigned short)((x + 0x7FFFu + ((x >> 16) & 1u)) >> 16);
    }
    ((ushort4*)dst)[i] = u;
}

// ---------------------------------------------------------------------------
// Kernel 1: V = Y @ W_M   ([R,D] @ [D,D] -> [R,D])
// ---------------------------------------------------------------------------
__global__ __launch_bounds__(256) void v_gemm_kernel(
    const float* __restrict__ Y, const float* __restrict__ WM,
    float* __restrict__ V)
{
    __shared__ float yt[32 * DD];
    const int r0 = blockIdx.x * 32;
    const int tid = threadIdx.x;

    for (int i = tid; i < 32 * DD; i += 256) {
        int j = i / DD, e = i - j * DD;
        int r = r0 + j;
        yt[i] = (r < RR) ? Y[r * DD + e] : 0.f;
    }
    __syncthreads();

    if (tid < DD) {
        float acc[32];
        #pragma unroll
        for (int j = 0; j < 32; ++j) acc[j] = 0.f;
        for (int e = 0; e < DD; ++e) {
            float w = WM[e * DD + tid];
            #pragma unroll
            for (int j = 0; j < 32; ++j) acc[j] += yt[j * DD + e] * w;
        }
        #pragma unroll
        for (int j = 0; j < 32; ++j) {
            int r = r0 + j;
            if (r < RR) V[r * DD + tid] = acc[j];
        }
    }
}

// ---------------------------------------------------------------------------
// Kernel 2: per-review attention -> p_t [R, A].  bf16 e_w staged in LDS.
// LDS ~18 KB -> 8 blocks/CU -> full occupancy.
// ---------------------------------------------------------------------------
__global__ __launch_bounds__(256, 8) void attn_kernel(
    const int* __restrict__ hist, const unsigned short* __restrict__ emb16,
    const float* __restrict__ V, const float* __restrict__ WW,
    const float* __restrict__ bW, float* __restrict__ PT)
{
    __shared__ __align__(16) unsigned short ew[LL * DD];  // 16000 B (bf16)
    __shared__ __align__(16) float v[DD];                 // 800 B
    __shared__ float zs[DD];                              // 800 B
    __shared__ float dxs[LL];
    __shared__ float ax[LL];
    __shared__ int   widx[LL];

    const int r = blockIdx.x;
    const int tid = threadIdx.x;

    if (tid < LL) widx[tid] = hist[r * LL + tid];
    if (tid >= 64 && tid < 64 + 50)   // separate wave does the V-row load
        ((float4*)v)[tid - 64] = ((const float4*)(V + (size_t)r * DD))[tid - 64];
    __syncthreads();

    // gather word embeddings: 40 rows x 25 uint4 (16B = 8 bf16) chunks
    for (int i = tid; i < LL * (DD / 8); i += 256) {
        int l = i / 25, c = i - l * 25;
        ((uint4*)(ew + l * DD))[c] =
            ((const uint4*)(emb16 + (size_t)widx[l] * DD))[c];
    }
    __syncthreads();

    const int wave = tid >> 6, lane = tid & 63;

    // dx[l] = e_w[l] . v   (wave per word; lanes 0..49 cover 4 elems each)
    for (int l = wave; l < LL; l += 4) {
        float p = 0.f;
        if (lane < 50) {
            int d0 = lane * 4;
            ushort4 e4 = *(const ushort4*)(ew + l * DD + d0);
            float4  v4 = *(const float4*)(v + d0);
            p = bf2f(e4.x) * v4.x + bf2f(e4.y) * v4.y
              + bf2f(e4.z) * v4.z + bf2f(e4.w) * v4.w;
        }
        #pragma unroll
        for (int off = 32; off; off >>= 1) p += __shfl_xor(p, off);
        if (lane == 0) dxs[l] = p;
    }
    __syncthreads();

    // softmax over L=40 in wave 0
    if (wave == 0) {
        float x = (lane < LL) ? dxs[lane] : -INFINITY;
        float m = x;
        #pragma unroll
        for (int off = 32; off; off >>= 1) m = fmaxf(m, __shfl_xor(m, off));
        float e = (lane < LL) ? expf(x - m) : 0.f;
        float s = e;
        #pragma unroll
        for (int off = 32; off; off >>= 1) s += __shfl_xor(s, off);
        if (lane < LL) ax[lane] = e / s;
    }
    __syncthreads();

    // z_s[d] = sum_l ax[l] * e_w[l][d]
    if (tid < DD) {
        float acc = 0.f;
        #pragma unroll 8
        for (int l = 0; l < LL; ++l) acc += ax[l] * bf2f(ew[l * DD + tid]);
        zs[tid] = acc;
    }
    __syncthreads();

    // p_t[r][a] = z_s . W_W[a] + b_W[a]   (8 threads per aspect)
    {
        int a = tid >> 3, j = tid & 7;
        float acc = 0.f;
        for (int d = j; d < DD; d += 8) acc += zs[d] * WW[a * DD + d];
        #pragma unroll
        for (int off = 4; off; off >>= 1) acc += __shfl_xor(acc, off);
        if (j == 0) PT[r * AA + a] = acc + bW[a];
    }
}

// ---------------------------------------------------------------------------
// Kernel 3: sparse [B,R] @ p_t [R,A] via gather + atomicAdd scatter.
// ---------------------------------------------------------------------------
__global__ __launch_bounds__(256) void spmm_kernel(
    const int* __restrict__ idx, const float* __restrict__ val,
    const float* __restrict__ PT, float* __restrict__ out, int nnz)
{
    int g = blockIdx.x * 256 + threadIdx.x;
    int n = g >> 5;
    if (n >= nnz) return;
    int a = g & 31;
    int row = idx[n];          // index[0][n]
    int col = idx[nnz + n];    // index[1][n]
    float w = val[n];
    atomicAdd(&out[row * AA + a], w * PT[col * AA + a]);
}

extern "C" void kernel_launch(void* const* d_in, const int* in_sizes, int n_in,
                              void* d_out, int out_size, void* d_ws, size_t ws_size,
                              hipStream_t stream) {
    const int*   hist = (const int*)d_in[0];
    const float* ypos = (const float*)d_in[1];
    const int*   uidx = (const int*)d_in[3];
    const float* uval = (const float*)d_in[4];
    const int*   iidx = (const int*)d_in[5];
    const float* ival = (const float*)d_in[6];
    const float* emb  = (const float*)d_in[8];
    const float* WM   = (const float*)d_in[9];
    const float* WW   = (const float*)d_in[10];
    const float* bW   = (const float*)d_in[11];

    unsigned short* emb16 = (unsigned short*)d_ws;            // [VOCAB, D] bf16, 20 MB
    float* V  = (float*)(emb16 + (size_t)VOCAB * DD);         // [R, D]  24 MB
    float* PT = V + (size_t)RR * DD;                          // [R, A]  3.84 MB
    float* out = (float*)d_out;                               // [2, B, A]

    const int nnz = in_sizes[4];

    hipMemsetAsync(d_out, 0, (size_t)out_size * sizeof(float), stream);

    cvt_bf16_kernel<<<(VOCAB * DD / 4 + 255) / 256, 256, 0, stream>>>(
        emb, emb16, VOCAB * DD / 4);
    v_gemm_kernel<<<(RR + 31) / 32, 256, 0, stream>>>(ypos, WM, V);
    attn_kernel<<<RR, 256, 0, stream>>>(hist, emb16, V, WW, bW, PT);

    const int spmm_blocks = (nnz * 32 + 255) / 256;
    spmm_kernel<<<spmm_blocks, 256, 0, stream>>>(uidx, uval, PT, out, nnz);
    spmm_kernel<<<spmm_blocks, 256, 0, stream>>>(iidx, ival, PT, out + BB * AA, nnz);
}